// Round 3
// baseline (464.380 us; speedup 1.0000x reference)
//
#include <hip/hip_runtime.h>
#include <math.h>

#define NCH 64
#define NB 8
#define RSEL 8
#define SPATIAL 110592          // 48*48*48
#define S4 27648                // SPATIAL/4 float4s per channel
#define PARTS 4                 // split-K partial blocks per channel map
#define CHUNK4 (S4 / PARTS)     // 6912 float4s per partial block
#define ITERS (CHUNK4 / 256)    // 27 float4s per thread
#define NBLOCKS (NB * NCH * PARTS)  // 2048 blocks = 8 blocks/CU

typedef float f4 __attribute__((ext_vector_type(4)));

// ---------------------------------------------------------------------------
// Kernel 1 (fused): per-(b,c) split-K partial sums; the LAST block (device
// atomic counter) additionally runs the 64-wide MLP + sigmoid + top-8 and
// writes idx_out. Saves a dedicated single-wave kernel launch.
// MLP tail is register-light (acc[8] k-loop) so __launch_bounds__(256,8)
// keeps the streaming phase at full 32 waves/CU occupancy.
// ---------------------------------------------------------------------------
__global__ __launch_bounds__(256, 8) void mean_mlp_kernel(
    const float* __restrict__ x,
    const float* __restrict__ w1, const float* __restrict__ b1,
    const float* __restrict__ w2, const float* __restrict__ b2,
    float* __restrict__ partials, int* __restrict__ idx_out,
    unsigned int* __restrict__ counter)
{
    const int bc   = blockIdx.x >> 2;   // 0..511  (b*64 + c)
    const int part = blockIdx.x & 3;
    const f4* p = (const f4*)(x + (size_t)bc * SPATIAL) + part * CHUNK4;
    float s = 0.f;
    #pragma unroll
    for (int i = 0; i < ITERS; ++i) {
        f4 v = p[i * 256 + threadIdx.x];
        s += (v.x + v.y) + (v.z + v.w);
    }
    #pragma unroll
    for (int o = 32; o >= 1; o >>= 1) s += __shfl_down(s, o, 64);
    __shared__ float ws4[4];
    __shared__ int last_flag;
    const int lane = threadIdx.x & 63;
    const int wv   = threadIdx.x >> 6;
    if (lane == 0) ws4[wv] = s;
    __syncthreads();
    if (threadIdx.x == 0) {
        partials[blockIdx.x] = (ws4[0] + ws4[1]) + (ws4[2] + ws4[3]);
        __threadfence();                       // publish partial before count
        unsigned int old = atomicAdd(counter, 1u);
        last_flag = (old == NBLOCKS - 1) ? 1 : 0;
    }
    __syncthreads();
    if (!last_flag) return;                    // block-uniform exit
    __threadfence();                           // acquire: see all partials

    // ---- MLP tail: wave 0 computes; waves 1-3 just ride the barriers ----
    const int j = threadIdx.x;                 // feature index for j < 64
    __shared__ float m[NB][NCH];
    __shared__ float h[NB][NCH];
    __shared__ float yv[NB][NCH];

    if (j < NCH) {
        #pragma unroll
        for (int b = 0; b < NB; ++b) {
            const float* pp = partials + (size_t)(b * NCH + j) * PARTS;
            m[b][j] = ((pp[0] + pp[1]) + (pp[2] + pp[3])) * (1.0f / (float)SPATIAL);
        }
    }
    __syncthreads();

    if (j < NCH) {                             // layer 1 + LeakyReLU
        float acc[NB];
        #pragma unroll
        for (int b = 0; b < NB; ++b) acc[b] = b1[j];
        for (int k = 0; k < NCH; ++k) {
            float wk = w1[j * NCH + k];
            #pragma unroll
            for (int b = 0; b < NB; ++b) acc[b] += m[b][k] * wk;
        }
        #pragma unroll
        for (int b = 0; b < NB; ++b) h[b][j] = acc[b] > 0.f ? acc[b] : 0.01f * acc[b];
    }
    __syncthreads();

    if (j < NCH) {                             // layer 2 + sigmoid
        float acc[NB];
        #pragma unroll
        for (int b = 0; b < NB; ++b) acc[b] = b2[j];
        for (int k = 0; k < NCH; ++k) {
            float wk = w2[j * NCH + k];
            #pragma unroll
            for (int b = 0; b < NB; ++b) acc[b] += h[b][k] * wk;
        }
        #pragma unroll
        for (int b = 0; b < NB; ++b) yv[b][j] = 1.0f / (1.0f + expf(-acc[b]));
    }
    __syncthreads();

    if (j < NCH) {                             // top-8, ties -> lower index
        for (int b = 0; b < NB; ++b) {
            float mine = yv[b][j];
            #pragma unroll
            for (int r = 0; r < RSEL; ++r) {
                float v = mine;
                int   c = j;
                #pragma unroll
                for (int o = 32; o >= 1; o >>= 1) {
                    float ov = __shfl_xor(v, o, 64);
                    int   oc = __shfl_xor(c, o, 64);
                    if (ov > v || (ov == v && oc < c)) { v = ov; c = oc; }
                }
                if (j == 0) idx_out[b * RSEL + r] = c;
                if (j == c) mine = -INFINITY;
            }
        }
    }
}

// ---------------------------------------------------------------------------
// Kernel 2: gather selected channels. grid = (27, 64). Reads hit L2/L3 (x
// just streamed, 226.5 MB < 256 MB L3); nontemporal stores keep the output
// (never re-read) from evicting x.
// ---------------------------------------------------------------------------
__global__ __launch_bounds__(256) void gather_kernel(const float* __restrict__ x,
                                                     const int* __restrict__ idx,
                                                     float* __restrict__ out) {
    const int pair = blockIdx.y;          // 0..63  (b*8 + r)
    const int b    = pair >> 3;
    const int ch   = idx[pair];
    const f4* src = (const f4*)(x + (size_t)(b * NCH + ch) * SPATIAL);
    f4*       dst = (f4*)(out + (size_t)pair * SPATIAL);
    const int base = blockIdx.x * 1024 + threadIdx.x;
    #pragma unroll
    for (int i = 0; i < 4; ++i) {
        f4 v = src[base + i * 256];
        __builtin_nontemporal_store(v, &dst[base + i * 256]);
    }
}

extern "C" void kernel_launch(void* const* d_in, const int* in_sizes, int n_in,
                              void* d_out, int out_size, void* d_ws, size_t ws_size,
                              hipStream_t stream) {
    const float* x  = (const float*)d_in[0];
    const float* w1 = (const float*)d_in[1];
    const float* b1 = (const float*)d_in[2];
    const float* w2 = (const float*)d_in[3];
    const float* b2 = (const float*)d_in[4];
    float* out = (float*)d_out;

    float*        partials = (float*)d_ws;                        // 2048 floats (8 KB)
    int*          idx      = (int*)((char*)d_ws + 8192);          // 64 ints
    unsigned int* counter  = (unsigned int*)((char*)d_ws + 8448); // 1 uint

    hipMemsetAsync(counter, 0, sizeof(unsigned int), stream);
    mean_mlp_kernel<<<dim3(NBLOCKS), dim3(256), 0, stream>>>(
        x, w1, b1, w2, b2, partials, idx, counter);
    gather_kernel<<<dim3(S4 / 1024, NB * RSEL), dim3(256), 0, stream>>>(x, idx, out);
}

// Round 4
// 375.930 us; speedup vs baseline: 1.2353x; 1.2353x over previous
//
#include <hip/hip_runtime.h>
#include <math.h>

#define NCH 64
#define NB 8
#define RSEL 8
#define SPATIAL 110592          // 48*48*48
#define S4 27648                // SPATIAL/4 float4s per channel
#define PARTS 4                 // split-K partial blocks per channel map
#define CHUNK4 (S4 / PARTS)     // 6912 float4s per partial block
#define ITERS (CHUNK4 / 256)    // 27 float4s per thread
#define BATCH 9                 // loads held in flight per round (27 = 3*9)

typedef float f4 __attribute__((ext_vector_type(4)));

// ---------------------------------------------------------------------------
// Kernel 1: per-(b,c) split-K partial sums. 2048 blocks = 8 blocks/CU.
// Loads batched 9 deep so ~36 VGPRs of f4 loads stay in flight per wave.
// NO device fences/atomics (R3 post-mortem: per-block agent-scope fences on
// multi-XCD gfx950 force L2 writeback/inv -> 229us pathological stall).
// ---------------------------------------------------------------------------
__global__ __launch_bounds__(256) void mean_kernel(const float* __restrict__ x,
                                                   float* __restrict__ partials) {
    const int bc   = blockIdx.x >> 2;   // 0..511  (b*64 + c)
    const int part = blockIdx.x & 3;
    const f4* p = (const f4*)(x + (size_t)bc * SPATIAL) + part * CHUNK4 + threadIdx.x;
    float s = 0.f;
    #pragma unroll
    for (int r = 0; r < ITERS / BATCH; ++r) {
        f4 v[BATCH];
        #pragma unroll
        for (int i = 0; i < BATCH; ++i) v[i] = p[(r * BATCH + i) * 256];
        #pragma unroll
        for (int i = 0; i < BATCH; ++i) s += (v[i].x + v[i].y) + (v[i].z + v[i].w);
    }
    // intra-wave reduction (wave = 64)
    #pragma unroll
    for (int o = 32; o >= 1; o >>= 1) s += __shfl_down(s, o, 64);
    __shared__ float ws[4];
    const int lane = threadIdx.x & 63;
    const int wv   = threadIdx.x >> 6;
    if (lane == 0) ws[wv] = s;
    __syncthreads();
    if (threadIdx.x == 0) {
        partials[blockIdx.x] = (ws[0] + ws[1]) + (ws[2] + ws[3]);
    }
}

// ---------------------------------------------------------------------------
// Kernel 2: combine partials -> means, MLP + sigmoid + top-8. One wave.
// ---------------------------------------------------------------------------
__global__ __launch_bounds__(64) void mlp_topk_kernel(const float* __restrict__ partials,
                                                      const float* __restrict__ w1,
                                                      const float* __restrict__ b1,
                                                      const float* __restrict__ w2,
                                                      const float* __restrict__ b2,
                                                      int* __restrict__ idx_out) {
    const int j = threadIdx.x;  // 0..63
    __shared__ float m[NB][NCH];
    __shared__ float h[NB][NCH];
    __shared__ float y[NB][NCH];

    #pragma unroll
    for (int b = 0; b < NB; ++b) {
        const float* pp = partials + (size_t)(b * NCH + j) * PARTS;
        m[b][j] = ((pp[0] + pp[1]) + (pp[2] + pp[3])) * (1.0f / (float)SPATIAL);
    }
    __syncthreads();

    // layer 1: h[b][j] = leaky_relu( sum_k m[b][k] * w1[j][k] + b1[j] )
    float wrow[NCH];
    #pragma unroll 8
    for (int k = 0; k < NCH; ++k) wrow[k] = w1[j * NCH + k];
    float bj = b1[j];
    #pragma unroll
    for (int b = 0; b < NB; ++b) {
        float acc = bj;
        #pragma unroll 8
        for (int k = 0; k < NCH; ++k) acc += m[b][k] * wrow[k];
        h[b][j] = acc > 0.f ? acc : 0.01f * acc;
    }
    __syncthreads();

    // layer 2: y[b][j] = sigmoid( sum_k h[b][k] * w2[j][k] + b2[j] )
    #pragma unroll 8
    for (int k = 0; k < NCH; ++k) wrow[k] = w2[j * NCH + k];
    bj = b2[j];
    #pragma unroll
    for (int b = 0; b < NB; ++b) {
        float acc = bj;
        #pragma unroll 8
        for (int k = 0; k < NCH; ++k) acc += h[b][k] * wrow[k];
        y[b][j] = 1.0f / (1.0f + expf(-acc));
    }
    __syncthreads();

    // top-8 per row, descending, ties -> lower index first
    for (int b = 0; b < NB; ++b) {
        float mine = y[b][j];
        #pragma unroll
        for (int r = 0; r < RSEL; ++r) {
            float v = mine;
            int   c = j;
            #pragma unroll
            for (int o = 32; o >= 1; o >>= 1) {
                float ov = __shfl_xor(v, o, 64);
                int   oc = __shfl_xor(c, o, 64);
                if (ov > v || (ov == v && oc < c)) { v = ov; c = oc; }
            }
            if (j == 0) idx_out[b * RSEL + r] = c;
            if (j == c) mine = -INFINITY;
        }
    }
}

// ---------------------------------------------------------------------------
// Kernel 3: gather selected channels. grid = (27, 64). Reads mostly hit
// L2/L3 (x just streamed, 226.5 MB < 256 MB L3); nontemporal stores keep
// the never-re-read output from evicting x.
// ---------------------------------------------------------------------------
__global__ __launch_bounds__(256) void gather_kernel(const float* __restrict__ x,
                                                     const int* __restrict__ idx,
                                                     float* __restrict__ out) {
    const int pair = blockIdx.y;          // 0..63  (b*8 + r)
    const int b    = pair >> 3;
    const int ch   = idx[pair];
    const f4* src = (const f4*)(x + (size_t)(b * NCH + ch) * SPATIAL);
    f4*       dst = (f4*)(out + (size_t)pair * SPATIAL);
    const int base = blockIdx.x * 1024 + threadIdx.x;
    #pragma unroll
    for (int i = 0; i < 4; ++i) {
        f4 v = src[base + i * 256];
        __builtin_nontemporal_store(v, &dst[base + i * 256]);
    }
}

extern "C" void kernel_launch(void* const* d_in, const int* in_sizes, int n_in,
                              void* d_out, int out_size, void* d_ws, size_t ws_size,
                              hipStream_t stream) {
    const float* x  = (const float*)d_in[0];
    const float* w1 = (const float*)d_in[1];
    const float* b1 = (const float*)d_in[2];
    const float* w2 = (const float*)d_in[3];
    const float* b2 = (const float*)d_in[4];
    float* out = (float*)d_out;

    float* partials = (float*)d_ws;                                     // 2048 floats
    int*   idx      = (int*)((char*)d_ws + NB * NCH * PARTS * sizeof(float)); // 64 ints

    mean_kernel<<<dim3(NB * NCH * PARTS), dim3(256), 0, stream>>>(x, partials);
    mlp_topk_kernel<<<dim3(1), dim3(64), 0, stream>>>(partials, w1, b1, w2, b2, idx);
    gather_kernel<<<dim3(S4 / 1024, NB * RSEL), dim3(256), 0, stream>>>(x, idx, out);
}